// Round 7
// baseline (191.638 us; speedup 1.0000x reference)
//
#include <hip/hip_runtime.h>

#define LOG2E 1.4426950408889634f

typedef __attribute__((address_space(3))) unsigned int lds_u32_t;
typedef const __attribute__((address_space(1))) unsigned int glb_u32_t;
typedef __fp16 h2v __attribute__((ext_vector_type(2)));
typedef __fp16 v8h __attribute__((ext_vector_type(8)));
typedef float  v4f __attribute__((ext_vector_type(4)));

union H2U { h2v h; unsigned int u; };
union V8U { unsigned int u[4]; v8h v; };

// Block = 256 threads = 4 waves; wave owns 16 rows. TPB=1 (fine-grain, no tail).
// Order: issue pred gll + scores loads FIRST -> weight prologue overlaps flight ->
// barrier (drains) -> per-quad topk/softmax -> stat into dead pred LDS ->
// one padded 16x16x32 f16 MFMA x 4 col-blocks for the MLP -> silu/w2 reduce -> out.
__global__ __launch_bounds__(256, 4) void lqe_mfma(
    const float* __restrict__ scores,
    const float* __restrict__ pred,
    const float* __restrict__ w1,   // [20][64]
    const float* __restrict__ b1,   // [64]
    const float* __restrict__ w2,   // [64]
    const float* __restrict__ b2,   // [1]
    float* __restrict__ out)
{
    __shared__ __align__(16) float predS[4 * 2112];   // per-wave chunks; stat tile reuses [0,576)
    __shared__ __align__(16) unsigned int wHf[1024];  // B-frag-ordered f16 w1 (4 KB)
    __shared__ __align__(16) float wSf[129];          // b1[0..63] w2[64..127] b2[128]
    __shared__ __align__(16) float qS[4][16];

    const int t = threadIdx.x, lane = t & 63, wv = t >> 6;
    const int tile = blockIdx.x;
    float* buf = predS + wv * 2112;

    // ---- 1) issue pred gll + scores loads FIRST (flight overlaps weight prologue) ----
    const float* gp = pred + (size_t)tile * 8448 + wv * 2112;
#pragma unroll
    for (int k = 0; k < 8; ++k)
        __builtin_amdgcn_global_load_lds((glb_u32_t*)(gp + 256*k + 4*lane),
                                         (lds_u32_t*)(buf + 256*k), 16, 0, 0);
    __builtin_amdgcn_global_load_lds((glb_u32_t*)(gp + 2048 + lane),
                                     (lds_u32_t*)(buf + 2048), 4, 0, 0);

    const size_t s4 = (size_t)tile * 1280 + wv * 320;
    const float4* sp = reinterpret_cast<const float4*>(scores) + s4;
    float4 sv0 = sp[lane], sv1 = sp[lane+64], sv2 = sp[lane+128],
           sv3 = sp[lane+192], sv4 = sp[lane+256];

    // ---- 2) weight prologue: B-frag pack. entry e=(b,l,d): holds f16 pair
    //        (w1[k0][n], w1[k0+1][n]), k0 = 8*(l>>4)+2d, n = 16b+(l&15), 0 if k0>=20.
#pragma unroll
    for (int m = 0; m < 4; ++m) {
        const int e  = t + 256*m;
        const int bb = e >> 8, l = (e >> 2) & 63, d = e & 3;
        const int n  = 16*bb + (l & 15);
        const int k0 = 8*(l >> 4) + 2*d;
        float a = 0.f, bfl = 0.f;
        if (k0 < 20) { a = w1[k0*64 + n]; bfl = w1[k0*64 + 64 + n]; }
        H2U hu; hu.h = __builtin_amdgcn_cvt_pkrtz(a, bfl);
        wHf[e] = hu.u;
    }
    if (t < 64) { wSf[t] = b1[t]; wSf[64 + t] = w2[t]; }
    if (t == 0) wSf[128] = b2[0];

    __syncthreads();   // compiler drains vmcnt+lgkm: pred in LDS, weights in LDS

    // ---- 3) per-quad topk + softmax: thread (r=lane>>2, c=lane&3) ----
    const int r = lane >> 2, c = lane & 3;
    const float* xp = buf + r*132 + c*33;
    float xs[33];
#pragma unroll
    for (int j = 0; j < 33; ++j) xs[j] = xp[j];
    asm volatile("s_waitcnt lgkmcnt(0)" ::: "memory");   // xs in regs; buf[0..576) reusable
    __builtin_amdgcn_sched_barrier(0);

    float t0 = -1e30f, t1 = -1e30f, t2 = -1e30f, t3 = -1e30f;
#pragma unroll
    for (int j = 0; j < 33; ++j) {
        float v  = xs[j];
        float r0 = fminf(t0, v);  t0 = fmaxf(t0, v);
        float r1 = fminf(t1, r0); t1 = fmaxf(t1, r0);
        float r2 = fminf(t2, r1); t2 = fmaxf(t2, r1);
        t3 = fmaxf(t3, r2);
    }
    float denom = 0.f;
#pragma unroll
    for (int j = 0; j < 33; ++j)
        denom += __builtin_amdgcn_exp2f((xs[j] - t0) * LOG2E);
    float rd = __builtin_amdgcn_rcpf(denom);

    float s5[5];
    s5[0] = rd;
    s5[1] = __builtin_amdgcn_exp2f((t1 - t0) * LOG2E) * rd;
    s5[2] = __builtin_amdgcn_exp2f((t2 - t0) * LOG2E) * rd;
    s5[3] = __builtin_amdgcn_exp2f((t3 - t0) * LOG2E) * rd;
    s5[4] = (s5[0] + s5[1] + s5[2] + s5[3]) * 0.25f;

    // ---- 4) stat tile [16][36] f32 into the dead pred chunk; zero-pad k=20..31 ----
    float* st = buf;
#pragma unroll
    for (int i = 0; i < 5; ++i) st[r*36 + 5*c + i] = s5[i];   // k = 5c+i
#pragma unroll
    for (int i = 0; i < 3; ++i) {
        const int e = 3*lane + i;                             // 192 zeros
        st[(e/12)*36 + 20 + (e%12)] = 0.f;
    }
    asm volatile("s_waitcnt lgkmcnt(0)" ::: "memory");
    __builtin_amdgcn_sched_barrier(0);

    // ---- 5) A-frag: lane holds stat[l&15][8*(l>>4)+j], j=0..7 ----
    const int arow = lane & 15, aq = lane >> 4;
    const float4* apv = reinterpret_cast<const float4*>(st + arow*36 + 8*aq);
    float4 af0 = apv[0], af1 = apv[1];
    V8U ua;
    { H2U h0; h0.h = __builtin_amdgcn_cvt_pkrtz(af0.x, af0.y); ua.u[0] = h0.u; }
    { H2U h1; h1.h = __builtin_amdgcn_cvt_pkrtz(af0.z, af0.w); ua.u[1] = h1.u; }
    { H2U h2; h2.h = __builtin_amdgcn_cvt_pkrtz(af1.x, af1.y); ua.u[2] = h2.u; }
    { H2U h3; h3.h = __builtin_amdgcn_cvt_pkrtz(af1.z, af1.w); ua.u[3] = h3.u; }
    const v8h afrag = ua.v;

    // ---- 6) MLP via 4 mfma (col blocks of 16 hidden units), bias in C ----
    const uint4* wfv = reinterpret_cast<const uint4*>(wHf);
    v4f acc[4];
#pragma unroll
    for (int bb = 0; bb < 4; ++bb) {
        uint4 bw = wfv[bb*64 + lane];
        V8U ub; ub.u[0]=bw.x; ub.u[1]=bw.y; ub.u[2]=bw.z; ub.u[3]=bw.w;
        const float bias = wSf[16*bb + arow];   // h = 16bb + (lane&15)
        v4f cc = { bias, bias, bias, bias };
        acc[bb] = __builtin_amdgcn_mfma_f32_16x16x32_f16(afrag, ub.v, cc, 0, 0, 0);
    }

    // ---- 7) silu + w2, reduce across the 16 col-lanes ----
    float qp0 = 0.f, qp1 = 0.f, qp2 = 0.f, qp3 = 0.f;
#pragma unroll
    for (int bb = 0; bb < 4; ++bb) {
        const float w2l = wSf[64 + 16*bb + arow];
        float v, sg;
        v = acc[bb][0]; sg = __builtin_amdgcn_rcpf(1.f + __builtin_amdgcn_exp2f(-v*LOG2E)); qp0 = fmaf(v*sg, w2l, qp0);
        v = acc[bb][1]; sg = __builtin_amdgcn_rcpf(1.f + __builtin_amdgcn_exp2f(-v*LOG2E)); qp1 = fmaf(v*sg, w2l, qp1);
        v = acc[bb][2]; sg = __builtin_amdgcn_rcpf(1.f + __builtin_amdgcn_exp2f(-v*LOG2E)); qp2 = fmaf(v*sg, w2l, qp2);
        v = acc[bb][3]; sg = __builtin_amdgcn_rcpf(1.f + __builtin_amdgcn_exp2f(-v*LOG2E)); qp3 = fmaf(v*sg, w2l, qp3);
    }
#pragma unroll
    for (int m = 1; m < 16; m <<= 1) {
        qp0 += __shfl_xor(qp0, m, 64);
        qp1 += __shfl_xor(qp1, m, 64);
        qp2 += __shfl_xor(qp2, m, 64);
        qp3 += __shfl_xor(qp3, m, 64);
    }
    if (arow == 0) {   // rows 4*aq + {0..3}
        const float bq = wSf[128];
        float4 qv = { qp0 + bq, qp1 + bq, qp2 + bq, qp3 + bq };
        *reinterpret_cast<float4*>(&qS[wv][4*aq]) = qv;
    }
    asm volatile("s_waitcnt lgkmcnt(0)" ::: "memory");
    __builtin_amdgcn_sched_barrier(0);

    // ---- 8) epilogue: wave writes its own 320 float4 of out = scores + q ----
    float4* op = reinterpret_cast<float4*>(out) + s4;
    {
        float qq; int idx;
        idx = lane;       qq = qS[wv][idx/20]; sv0.x+=qq; sv0.y+=qq; sv0.z+=qq; sv0.w+=qq; op[idx] = sv0;
        idx = lane +  64; qq = qS[wv][idx/20]; sv1.x+=qq; sv1.y+=qq; sv1.z+=qq; sv1.w+=qq; op[idx] = sv1;
        idx = lane + 128; qq = qS[wv][idx/20]; sv2.x+=qq; sv2.y+=qq; sv2.z+=qq; sv2.w+=qq; op[idx] = sv2;
        idx = lane + 192; qq = qS[wv][idx/20]; sv3.x+=qq; sv3.y+=qq; sv3.z+=qq; sv3.w+=qq; op[idx] = sv3;
        idx = lane + 256; qq = qS[wv][idx/20]; sv4.x+=qq; sv4.y+=qq; sv4.z+=qq; sv4.w+=qq; op[idx] = sv4;
    }
}

extern "C" void kernel_launch(void* const* d_in, const int* in_sizes, int n_in,
                              void* d_out, int out_size, void* d_ws, size_t ws_size,
                              hipStream_t stream) {
    const float* scores = (const float*)d_in[0];
    const float* pred   = (const float*)d_in[1];
    const float* w1     = (const float*)d_in[2];
    const float* b1     = (const float*)d_in[3];
    const float* w2     = (const float*)d_in[4];
    const float* b2     = (const float*)d_in[5];
    float* out = (float*)d_out;

    const int nrows = in_sizes[1] / 132;   // 800000 = 12500 * 64
    const int grid  = nrows / 64;

    hipLaunchKernelGGL(lqe_mfma, dim3(grid), dim3(256), 0, stream,
                       scores, pred, w1, b1, w2, b2, out);
}

// Round 9
// 144.265 us; speedup vs baseline: 1.3284x; 1.3284x over previous
//
#include <hip/hip_runtime.h>

#define LOG2E 1.4426950408889634f

typedef __attribute__((address_space(3))) unsigned int lds_u32_t;
typedef const __attribute__((address_space(1))) unsigned int glb_u32_t;
typedef __fp16 h2 __attribute__((ext_vector_type(2)));
typedef __fp16 h8 __attribute__((ext_vector_type(8)));
typedef float  f4 __attribute__((ext_vector_type(4)));   // native vec: ok for nontemporal builtins

// Persistent: 1024 blocks (4/CU exactly), grid-stride over tiles.
// Block = 4 independent waves; wave owns 16 rows/tile. Weight prologue ONCE.
// Loop: issue pred gll (NT) -> issue scores loads -> vmcnt(5) (retires pred,
// keeps scores + older stores in flight) -> topk/softmax/dot2-MLP -> vmcnt(0)
// -> nontemporal out stores. No block barrier in the loop.
__global__ __launch_bounds__(256, 4) void lqe_pers(
    const float* __restrict__ scores,
    const float* __restrict__ pred,
    const float* __restrict__ w1,   // [20][64]
    const float* __restrict__ b1,   // [64]
    const float* __restrict__ w2,   // [64]
    const float* __restrict__ b2,   // [1]
    float* __restrict__ out,
    int ntiles)
{
    __shared__ __align__(16) float predS[4 * 2112];  // 33792 B, per-wave chunks
    __shared__ __align__(16) h2    wH[640];          // wH[p*64+h] = (w1[2p][h], w1[2p+1][h])
    __shared__ __align__(16) float wSf[132];         // b1[0..63] w2[64..127] b2[128]

    const int t    = threadIdx.x;
    const int lane = t & 63;
    const int wv   = t >> 6;

    // ---- one-time weight prologue (only barrier in the kernel) ----
    for (int e = t; e < 640; e += 256) {
        const int p = e >> 6, h = e & 63;
        float a = w1[p * 128 + h];                  // w1[2p][h]
        float b = w1[p * 128 + 64 + h];             // w1[2p+1][h]
        wH[e] = __builtin_amdgcn_cvt_pkrtz(a, b);
    }
    if (t < 64) { wSf[t] = b1[t]; wSf[64 + t] = w2[t]; }
    if (t == 0) wSf[128] = b2[0];
    __syncthreads();

    float* buf = predS + wv * 2112;

    for (int tile = blockIdx.x; tile < ntiles; tile += gridDim.x) {
        // ---- stage this wave's 16 rows of pred (9 gll, NT so L3 isn't thrashed) ----
        const float* gp = pred + (size_t)tile * 8448 + wv * 2112;
#pragma unroll
        for (int k = 0; k < 8; ++k) {
            __builtin_amdgcn_global_load_lds((glb_u32_t*)(gp + 256 * k + 4 * lane),
                                             (lds_u32_t*)(buf + 256 * k), 16, 0, 2);
        }
        __builtin_amdgcn_global_load_lds((glb_u32_t*)(gp + 2048 + lane),
                                         (lds_u32_t*)(buf + 2048), 4, 0, 2);

        // ---- scores loads (temporal: want these L3-resident across replays) ----
        const size_t s4 = (size_t)tile * 1280 + wv * 320;
        const f4* sp = reinterpret_cast<const f4*>(scores) + s4;
        f4 sv0 = sp[lane +   0];
        f4 sv1 = sp[lane +  64];
        f4 sv2 = sp[lane + 128];
        f4 sv3 = sp[lane + 192];
        f4 sv4 = sp[lane + 256];

        // retire pred gll (9) + any older stores; keep scores (5) in flight.
        // rule-18 fence so dependent ds_reads can't hoist above the wait.
        asm volatile("s_waitcnt vmcnt(5)" ::: "memory");
        __builtin_amdgcn_sched_barrier(0);

        // ---- thread (r = lane>>2, c = lane&3) owns one corner of one row ----
        const int r = lane >> 2, c = lane & 3;
        const float* xp = buf + r * 132 + c * 33;   // bank = (lane+j)%32 -> 2-way, free
        float xs[33];
#pragma unroll
        for (int j = 0; j < 33; ++j) xs[j] = xp[j];

        // branchless top-4 (sorted desc)
        float t0 = -1e30f, t1 = -1e30f, t2 = -1e30f, t3 = -1e30f;
#pragma unroll
        for (int j = 0; j < 33; ++j) {
            float v  = xs[j];
            float r0 = fminf(t0, v);  t0 = fmaxf(t0, v);
            float r1 = fminf(t1, r0); t1 = fmaxf(t1, r0);
            float r2 = fminf(t2, r1); t2 = fmaxf(t2, r1);
            t3 = fmaxf(t3, r2);
        }
        float denom = 0.f;
#pragma unroll
        for (int j = 0; j < 33; ++j)
            denom += __builtin_amdgcn_exp2f((xs[j] - t0) * LOG2E);
        float rd = __builtin_amdgcn_rcpf(denom);

        float s5[5];
        s5[0] = rd;
        s5[1] = __builtin_amdgcn_exp2f((t1 - t0) * LOG2E) * rd;
        s5[2] = __builtin_amdgcn_exp2f((t2 - t0) * LOG2E) * rd;
        s5[3] = __builtin_amdgcn_exp2f((t3 - t0) * LOG2E) * rd;
        s5[4] = (s5[0] + s5[1] + s5[2] + s5[3]) * 0.25f;

        // quad-local exchange: every thread gets all 20 stats of its row
        float stat[20];
#pragma unroll
        for (int i = 0; i < 20; ++i)
            stat[i] = __shfl(s5[i % 5], i / 5, 4);

        // pack stats into 10 half2
        h2 spk[10];
#pragma unroll
        for (int p = 0; p < 10; ++p)
            spk[p] = __builtin_amdgcn_cvt_pkrtz(stat[2 * p], stat[2 * p + 1]);

        // MLP: thread c computes hidden units [16c..16c+15] via v_dot2_f32_f16
        float hacc[16];
        {
            const f4* b1v = reinterpret_cast<const f4*>(wSf + 16 * c);
#pragma unroll
            for (int k = 0; k < 4; ++k) {
                f4 b = b1v[k];
                hacc[4*k+0]=b.x; hacc[4*k+1]=b.y; hacc[4*k+2]=b.z; hacc[4*k+3]=b.w;
            }
        }
#pragma unroll
        for (int p = 0; p < 10; ++p) {
            const h8* wp = reinterpret_cast<const h8*>(wH + p * 64 + 16 * c);
#pragma unroll
            for (int k = 0; k < 4; ++k) {
                h8 w8 = wp[k];
#pragma unroll
                for (int e = 0; e < 4; ++e) {
                    h2 w; w[0] = w8[2*e]; w[1] = w8[2*e+1];
#if __has_builtin(__builtin_amdgcn_fdot2)
                    hacc[4*k+e] = __builtin_amdgcn_fdot2(spk[p], w, hacc[4*k+e], false);
#else
                    hacc[4*k+e] = fmaf((float)spk[p][0], (float)w[0],
                                  fmaf((float)spk[p][1], (float)w[1], hacc[4*k+e]));
#endif
                }
            }
        }

        float q = 0.f;
        {
            const f4* w2v = reinterpret_cast<const f4*>(wSf + 64 + 16 * c);
#pragma unroll
            for (int k = 0; k < 4; ++k) {
                f4 w = w2v[k];
#pragma unroll
                for (int e = 0; e < 4; ++e) {
                    float v  = hacc[4*k+e];
                    float sg = __builtin_amdgcn_rcpf(1.f + __builtin_amdgcn_exp2f(-v * LOG2E));
                    float we = w[e];
                    q = fmaf(v * sg, we, q);
                }
            }
        }
        q += __shfl_xor(q, 1, 4);
        q += __shfl_xor(q, 2, 4);      // all 4 lanes of the quad hold the row's sum
        q += wSf[128];

        // scores definitely resident before use
        asm volatile("s_waitcnt vmcnt(0)" ::: "memory");

        // ---- epilogue: nontemporal out = scores + q (write-once stream) ----
        f4* op = reinterpret_cast<f4*>(out) + s4;
        {
            float qq; int idx, rl;
            idx = lane +   0; rl = idx / 20; qq = __shfl(q, rl * 4, 64);
            sv0 += qq; __builtin_nontemporal_store(sv0, &op[idx]);
            idx = lane +  64; rl = idx / 20; qq = __shfl(q, rl * 4, 64);
            sv1 += qq; __builtin_nontemporal_store(sv1, &op[idx]);
            idx = lane + 128; rl = idx / 20; qq = __shfl(q, rl * 4, 64);
            sv2 += qq; __builtin_nontemporal_store(sv2, &op[idx]);
            idx = lane + 192; rl = idx / 20; qq = __shfl(q, rl * 4, 64);
            sv3 += qq; __builtin_nontemporal_store(sv3, &op[idx]);
            idx = lane + 256; rl = idx / 20; qq = __shfl(q, rl * 4, 64);
            sv4 += qq; __builtin_nontemporal_store(sv4, &op[idx]);
        }
    }
}

extern "C" void kernel_launch(void* const* d_in, const int* in_sizes, int n_in,
                              void* d_out, int out_size, void* d_ws, size_t ws_size,
                              hipStream_t stream) {
    const float* scores = (const float*)d_in[0];
    const float* pred   = (const float*)d_in[1];
    const float* w1     = (const float*)d_in[2];
    const float* b1     = (const float*)d_in[3];
    const float* w2     = (const float*)d_in[4];
    const float* b2     = (const float*)d_in[5];
    float* out = (float*)d_out;

    const int nrows  = in_sizes[1] / 132;   // 800000
    const int ntiles = nrows / 64;          // 12500 tiles of 64 rows
    const int grid   = 1024;                // 4 blocks/CU x 256 CU, persistent

    hipLaunchKernelGGL(lqe_pers, dim3(grid), dim3(256), 0, stream,
                       scores, pred, w1, b1, w2, b2, out, ntiles);
}